// Round 7
// baseline (925.546 us; speedup 1.0000x reference)
//
#include <hip/hip_runtime.h>
#include <cstdint>
#include <cstddef>

#define TSTEPS 512
#define INP    24
#define HID    128
#define BB     4      // batch elems per block; 256 blocks (1/CU)
#define NKT    5      // K = 24 x + 128 h + 8 pad = 160 = 5 tiles of 32
#define VSTR   168    // v[] column stride in fp16 elems

typedef __attribute__((ext_vector_type(8))) _Float16 half8;   // 8 x fp16 (4 VGPRs)
typedef __attribute__((ext_vector_type(4))) float f32x4;

__device__ __forceinline__ float sigm_f(float v) {
    return 1.0f / (1.0f + __expf(-v));
}
__device__ __forceinline__ float tanh_f(float v) {
    float a = fabsf(v);
    float e = __expf(-2.0f * a);
    float r = (1.0f - e) / (1.0f + e);
    return v < 0.0f ? -r : r;
}
__device__ __forceinline__ unsigned pack2h(float a, float b) {
    union { _Float16 h[2]; unsigned u; } z;
    z.h[0] = (_Float16)a; z.h[1] = (_Float16)b;   // v_cvt_f16_f32, RTN
    return z.u;
}

// ROUND LESSONS ENCODED:
//  R1: VGPR-cap betrayal -> scratch spill shows as WRITE_SIZE GBs. Watch it.
//  R2: runtime-varying index into per-thread arrays demotes to memory.
//  R3: fp32 VALU ~3x too slow; use MFMA.
//  R4/R5: total time == per-block time (blocks run concurrently).
//  R6: mfma ~19.4 cyc/SIMD (4.85 is per-CU). Phases sum.
//  R7: LDS layouts at conflict minimum; residual counter = intrinsic b128 cost.
//  R8: LDS pipe is PER-CU; redistribution round trip ~1000 LDS cyc/ts.
//  R9: single-pass fp16 weights/state; ranges safe, absmax ~2^-11.
//  R10: wave-local redistribution -> ONE barrier/ts. 619->542us.
//       Residual 2447 cyc/ts = 776 mfma pipe + ~1670 serial-chain.
//  R11/R12: occupancy attrs clamp VGPR 96->64 -> spill -> 777us.
//  R13: no attr: VGPR 96, no spill, but HW still runs 1 block/CU
//       (2 serial rounds, 957us). Don't depend on residency rules.
//  R14: dual-group (2x mfma work/wave to "fill stalls"): wall GREW by
//       exactly the added mfma time +340. PROOF the non-mfma 1670 cyc is
//       a per-wave SERIAL CHAIN (dsread lat -> mfma drain -> LDS round
//       trip -> trans -> barrier), not fillable idle slots. Reverted.
//  R15 (this): DELETE THE LDS GATE ROUND-TRIP. With one accumulator per
//      gate, mfma C/D layout (col=lane&15=batch, row=quad*4+r=unit) means
//      lane (quad,ncol) ALREADY holds i,f,g,o for the same 4 cells
//      (unit wv*16+quad*4+r, batch ncol) in matching reg slots. Cell
//      update is elementwise -> do it in-register on lanes ncol<4:
//      bias[4][4] + c4[4] per lane (compile-time indices), pack 4 fp16,
//      ONE ds_write_b64 of h. part_s deleted. Serial chain loses 2 LDS
//      latencies + 8 LDS ops; trans issue x4 (separate pipe, ILP'd).
//      Predict 430-470us, bank-conflict ~2.8e7, LDS ~12KB.
//
// Per ts: gates[512 x 16] = W[512 x 160] @ v[160 x 16], batch cols 0..3 real.
// mfma_f32_16x16x32_f16:
//   A-frag: lane holds A[m=lane&15][k=quad*8+j]
//   B-frag: lane holds B[k=quad*8+j][n=lane&15]
//   C/D:    col=lane&15, row=quad*4+reg
__global__ __launch_bounds__(512)
void lstm_fused(
    const float* __restrict__ x,      // [B, T, 24]
    const float* __restrict__ addin,  // [B, 2]
    const float* __restrict__ W_ih,   // [512, 24]
    const float* __restrict__ W_hh,   // [512, 128]
    const float* __restrict__ b_ih,   // [512]
    const float* __restrict__ b_hh,   // [512]
    const float* __restrict__ W1,     // [64, 130]
    const float* __restrict__ b1,     // [64]
    const float* __restrict__ W2,     // [3, 64]
    const float* __restrict__ b2,     // [3]
    float* __restrict__ out)          // [B, 3]
{
    __shared__ _Float16 v_s[2][16 * VSTR];   // [buf][n][k]; n>=BB stays 0
    __shared__ float z_s[BB][64];

    const int t    = threadIdx.x;      // 512 threads = 8 waves
    const int lane = t & 63;
    const int wv   = t >> 6;           // 0..7: owns unit rows wv*16..+15 (x4 gates)
    const int ncol = lane & 15;        // batch col (0..3 real)
    const int quad = lane >> 4;
    const int b0   = blockIdx.x * BB;

    // ---- persistent A-fragments (fp16) ----
    half8 A_w[4][NKT];
    #pragma unroll
    for (int g = 0; g < 4; ++g) {
        const int row = g * HID + wv * 16 + ncol;
        #pragma unroll
        for (int kt = 0; kt < NKT; ++kt) {
            half8 frag;
            #pragma unroll
            for (int j = 0; j < 8; ++j) {
                const int k = kt * 32 + quad * 8 + j;
                float w = 0.0f;
                if (k < INP)            w = W_ih[row * INP + k];
                else if (k < INP + HID) w = W_hh[row * HID + (k - INP)];
                frag[j] = (_Float16)w;
            }
            A_w[g][kt] = frag;
        }
    }

    // in-register consumer state: this lane owns cells
    // (unit = wv*16 + quad*4 + r, batch = ncol) for r = 0..3 (ncol<BB real)
    float bias[4][4];   // [gate][r] — compile-time indexed (R2)
    #pragma unroll
    for (int g = 0; g < 4; ++g) {
        #pragma unroll
        for (int r = 0; r < 4; ++r) {
            const int u = wv * 16 + quad * 4 + r;
            bias[g][r] = b_ih[g * HID + u] + b_hh[g * HID + u];
        }
    }
    float c4[4] = {0.f, 0.f, 0.f, 0.f};

    // x-staging role: t<48 handles batch xb, k-pair kk*2
    const int xb = t / 12;
    const int kk = t - xb * 12;

    // ---- init: zero both buffers (cols >= BB and pads stay 0), stage x(0) ----
    for (int i = t; i < 16 * VSTR; i += 512) {
        v_s[0][i] = (_Float16)0.0f; v_s[1][i] = (_Float16)0.0f;
    }
    __syncthreads();
    if (t < 48) {
        const float2 xv = *(const float2*)(x + ((size_t)(b0 + xb) * TSTEPS) * INP + kk * 2);
        *(unsigned*)&v_s[0][xb * VSTR + kk * 2] = pack2h(xv.x, xv.y);
    }
    // prime distance-2 x queue: xq = x(1)
    float2 xq = {0.f, 0.f};
    if (t < 48) {
        xq = *(const float2*)(x + ((size_t)(b0 + xb) * TSTEPS + 1) * INP + kk * 2);
    }
    __syncthreads();

    // ---- recurrence: ONE barrier per ts, no gate redistribution ----
    #pragma unroll 2
    for (int ts = 0; ts < TSTEPS; ++ts) {
        const int pb = ts & 1, nb = pb ^ 1;

        // top: issue x(ts+2) load; stage x(ts+1)=xq into nb (read only next ts)
        float2 xn = {0.f, 0.f};
        if (t < 48) {
            const int tsn = (ts + 2 < TSTEPS) ? ts + 2 : TSTEPS - 1;
            xn = *(const float2*)(x + ((size_t)(b0 + xb) * TSTEPS + tsn) * INP + kk * 2);
            *(unsigned*)&v_s[nb][xb * VSTR + kk * 2] = pack2h(xq.x, xq.y);
        }

        // MFMA phase: 5 kt x 4 gates = 20 mfma per wave (4 independent chains)
        const _Float16* vh = v_s[pb];
        f32x4 ai = {0.f, 0.f, 0.f, 0.f}, af = ai, ag = ai, ao = ai;
        #pragma unroll
        for (int kt = 0; kt < NKT; ++kt) {
            const half8 bh = *(const half8*)(vh + ncol * VSTR + kt * 32 + quad * 8);
            ai = __builtin_amdgcn_mfma_f32_16x16x32_f16(A_w[0][kt], bh, ai, 0, 0, 0);
            af = __builtin_amdgcn_mfma_f32_16x16x32_f16(A_w[1][kt], bh, af, 0, 0, 0);
            ag = __builtin_amdgcn_mfma_f32_16x16x32_f16(A_w[2][kt], bh, ag, 0, 0, 0);
            ao = __builtin_amdgcn_mfma_f32_16x16x32_f16(A_w[3][kt], bh, ao, 0, 0, 0);
        }

        // in-register cell update: lane (quad,ncol<4) owns 4 cells; all four
        // gates for cell r are ai[r],af[r],ag[r],ao[r] — no LDS round trip.
        if (ncol < BB) {
            float hh[4];
            #pragma unroll
            for (int r = 0; r < 4; ++r) {
                const float gi = sigm_f(ai[r] + bias[0][r]);
                const float gf = sigm_f(af[r] + bias[1][r]);
                const float gg = tanh_f(ag[r] + bias[2][r]);
                const float go = sigm_f(ao[r] + bias[3][r]);
                c4[r] = gf * c4[r] + gi * gg;
                hh[r] = go * tanh_f(c4[r]);
            }
            // pack 4 fp16 h values, one 8B store (8B-aligned; banks distinct)
            uint2 uu;
            uu.x = pack2h(hh[0], hh[1]);
            uu.y = pack2h(hh[2], hh[3]);
            *(uint2*)&v_s[nb][ncol * VSTR + INP + wv * 16 + quad * 4] = uu;
        }

        // roll x queue
        if (t < 48) xq = xn;

        // single cross-wave hazard: all h(ts) visible before B-frag reads(ts+1)
        __syncthreads();
    }

    // ---- FC head: final h is in buffer 0 (ts=511 -> nb=0); h is fp16 ----
    if (t < 64 * BB) {
        const int b = t >> 6, u = t & 63;
        const float* w = W1 + u * 130;
        float a = b1[u];
        #pragma unroll 16
        for (int k = 0; k < HID; ++k) {
            const float hv = (float)v_s[0][b * VSTR + INP + k];
            a += fmaxf(hv, 0.0f) * w[k];
        }
        const float a0 = addin[(size_t)(b0 + b) * 2 + 0];
        const float a1 = addin[(size_t)(b0 + b) * 2 + 1];
        a += fmaxf(a0, 0.0f) * w[128] + fmaxf(a1, 0.0f) * w[129];
        z_s[b][u] = fmaxf(a, 0.0f);
    }
    __syncthreads();
    if (t < 3 * BB) {
        const int b = t / 3, o = t - 3 * b;
        const float* w = W2 + o * 64;
        float a = b2[o];
        #pragma unroll
        for (int k = 0; k < 64; ++k)
            a += z_s[b][k] * w[k];
        out[(size_t)(b0 + b) * 3 + o] = a;
    }
}

extern "C" void kernel_launch(void* const* d_in, const int* in_sizes, int n_in,
                              void* d_out, int out_size, void* d_ws, size_t ws_size,
                              hipStream_t stream) {
    const float* x     = (const float*)d_in[0];
    const float* addin = (const float*)d_in[1];
    const float* W_ih  = (const float*)d_in[2];
    const float* W_hh  = (const float*)d_in[3];
    const float* b_ih  = (const float*)d_in[4];
    const float* b_hh  = (const float*)d_in[5];
    const float* W1    = (const float*)d_in[6];
    const float* b1    = (const float*)d_in[7];
    const float* W2    = (const float*)d_in[8];
    const float* b2    = (const float*)d_in[9];
    float* outp        = (float*)d_out;

    const int B = in_sizes[0] / (TSTEPS * INP);   // 1024
    const int grid = B / BB;                      // 256 blocks (1 per CU)

    lstm_fused<<<grid, 512, 0, stream>>>(x, addin, W_ih, W_hh, b_ih, b_hh,
                                         W1, b1, W2, b2, outp);
}

// Round 8
// 465.893 us; speedup vs baseline: 1.9866x; 1.9866x over previous
//
#include <hip/hip_runtime.h>
#include <cstdint>
#include <cstddef>

#define TSTEPS 512
#define INP    24
#define HID    128
#define BB     4      // batch elems per block; 256 blocks (1/CU)
#define NKT    5      // K = 128 h + 24 x + 8 pad = 160 = 5 tiles of 32
#define VSTR   168    // v[] column stride in fp16 elems: [h 0..127 | x 128..151 | pad]

typedef __attribute__((ext_vector_type(8))) _Float16 half8;   // 8 x fp16 (4 VGPRs)
typedef __attribute__((ext_vector_type(4))) float f32x4;

__device__ __forceinline__ float rcp_f(float v) { return __builtin_amdgcn_rcpf(v); }
// fast sigmoid: exp + rcp (no precise-div sequence); ~1ulp rcp fine at fp16 state
__device__ __forceinline__ float sigm_f(float v) {
    return rcp_f(1.0f + __expf(-v));
}
// branchless tanh: 1 - 2/(1+e^{2v}); saturates correctly at +-inf, no fabs/select
__device__ __forceinline__ float tanh_f(float v) {
    return 1.0f - 2.0f * rcp_f(1.0f + __expf(2.0f * v));
}
__device__ __forceinline__ unsigned pack2h(float a, float b) {
    union { _Float16 h[2]; unsigned u; } z;
    z.h[0] = (_Float16)a; z.h[1] = (_Float16)b;   // v_cvt_f16_f32, RTN
    return z.u;
}

// ROUND LESSONS ENCODED:
//  R1: VGPR-cap betrayal -> scratch spill shows as WRITE_SIZE GBs. Watch it.
//  R2: runtime-varying index into per-thread arrays demotes to memory.
//  R3: fp32 VALU ~3x too slow; use MFMA.
//  R4/R5: total time == per-block time (blocks run concurrently).
//  R6: mfma ~19.4 cyc/SIMD (4.85 is per-CU). Phases sum.
//  R7: LDS layouts at conflict minimum; residual counter = intrinsic b128 cost.
//  R8: LDS pipe is PER-CU; redistribution round trip ~1000 LDS cyc/ts.
//  R9: single-pass fp16 weights/state; ranges safe, absmax ~2^-11.
//  R10: wave-local redistribution -> ONE barrier/ts. 619->542us.
//       Residual 2447 cyc/ts = 776 mfma pipe + ~1670 serial-chain.
//  R11/R12: occupancy attrs clamp VGPR 96->64 -> spill -> 777us.
//  R13: no attr: VGPR 96 no spill, but HW still 1 block/CU. Don't depend
//       on residency rules.
//  R14: 2x mfma work/wave to "fill stalls": wall grew by the added mfma.
//       The non-mfma 1670 cyc is a per-wave SERIAL CHAIN, not idle slots.
//  R15: in-register cell update on 16 lanes x 4 cells: VALU issue is
//       per-wave regardless of exec mask -> consumer stream x4 -> VALUBusy
//       76%, 925us. LESSON: elementwise work MUST stay spread across all
//       64 lanes; the LDS redistribution is what buys that.
//  R16 (this): shorten the chain, keep R10 shape. (a) bias folded into
//      mfma C-init (consumer drops 4 adds); (b) rcp-based sigm +
//      branchless tanh (consumer ~75 -> ~28 instrs, no div sequences);
//      (c) v reordered [h|x|pad] so kt4 is pure-x: compute next-ts x-tile
//      mfma PRE-barrier (independent of consumer -> overlaps its trans
//      chain on the mfma pipe), post-barrier phase = 4 reads + 16 mfma.
//      x staged 3 ahead; all cross-wave x hazards have a barrier between.
//      Predict 440-480us, VALUBusy 30-36, WRITE_SIZE ~16B else revert.
//
// Per ts: gates[512 x 16] = W[512 x 160] @ v[160 x 16], batch cols 0..3 real.
// mfma_f32_16x16x32_f16:
//   A-frag: lane holds A[m=lane&15][k=quad*8+j]
//   B-frag: lane holds B[k=quad*8+j][n=lane&15]
//   C/D:    col=lane&15, row=quad*4+reg
__global__ __launch_bounds__(512)
void lstm_fused(
    const float* __restrict__ x,      // [B, T, 24]
    const float* __restrict__ addin,  // [B, 2]
    const float* __restrict__ W_ih,   // [512, 24]
    const float* __restrict__ W_hh,   // [512, 128]
    const float* __restrict__ b_ih,   // [512]
    const float* __restrict__ b_hh,   // [512]
    const float* __restrict__ W1,     // [64, 130]
    const float* __restrict__ b1,     // [64]
    const float* __restrict__ W2,     // [3, 64]
    const float* __restrict__ b2,     // [3]
    float* __restrict__ out)          // [B, 3]
{
    __shared__ _Float16 v_s[2][16 * VSTR];   // [buf][n][k']; k'<128 h, 128..151 x
    __shared__ float part_s[8][256];         // per-wave slice: [g*64 + b*16 + u]
    __shared__ float z_s[BB][64];

    const int t    = threadIdx.x;      // 512 threads = 8 waves
    const int lane = t & 63;
    const int wv   = t >> 6;           // 0..7: owns unit rows wv*16..+15 (x4 gates)
    const int ncol = lane & 15;        // batch col (0..3 real)
    const int quad = lane >> 4;
    const int b0   = blockIdx.x * BB;

    // ---- persistent A-fragments (fp16), k' layout: [W_hh | W_ih | 0] ----
    half8 A_w[4][NKT];
    #pragma unroll
    for (int g = 0; g < 4; ++g) {
        const int row = g * HID + wv * 16 + ncol;
        #pragma unroll
        for (int kt = 0; kt < NKT; ++kt) {
            half8 frag;
            #pragma unroll
            for (int j = 0; j < 8; ++j) {
                const int k = kt * 32 + quad * 8 + j;
                float w = 0.0f;
                if (k < HID)            w = W_hh[row * HID + k];
                else if (k < HID + INP) w = W_ih[row * INP + (k - HID)];
                frag[j] = (_Float16)w;
            }
            A_w[g][kt] = frag;
        }
    }

    // bias as mfma C-init: biasv[g][r] for row quad*4+r (same for all cols)
    f32x4 biasv[4];
    #pragma unroll
    for (int g = 0; g < 4; ++g) {
        #pragma unroll
        for (int r = 0; r < 4; ++r) {
            const int u = wv * 16 + quad * 4 + r;
            biasv[g][r] = b_ih[g * HID + u] + b_hh[g * HID + u];
        }
    }

    // consumer role: lane -> (batch cb, unit cu) of THIS wave's 16 units
    const int cb = lane & 3;           // batch 0..3
    const int cu = lane >> 2;          // unit-local 0..15
    const int uj = wv * 16 + cu;       // absolute unit
    float c_reg = 0.0f;
    float* const pw = &part_s[wv][0];
    const int ci = cb * 16 + cu;

    // x-staging role: t<48 handles batch xb, k-pair kk*2
    const int xb = t / 12;
    const int kk = t - xb * 12;
    const size_t xrow = (size_t)(b0 + xb) * TSTEPS;

    // ---- init: zero both buffers; stage x(0)->buf0, x(1)->buf1; xq=x(2) ----
    for (int i = t; i < 16 * VSTR; i += 512) {
        v_s[0][i] = (_Float16)0.0f; v_s[1][i] = (_Float16)0.0f;
    }
    __syncthreads();
    if (t < 48) {
        const float2 x0 = *(const float2*)(x + (xrow + 0) * INP + kk * 2);
        const float2 x1 = *(const float2*)(x + (xrow + 1) * INP + kk * 2);
        *(unsigned*)&v_s[0][xb * VSTR + HID + kk * 2] = pack2h(x0.x, x0.y);
        *(unsigned*)&v_s[1][xb * VSTR + HID + kk * 2] = pack2h(x1.x, x1.y);
    }
    float2 xq = {0.f, 0.f};
    if (t < 48) {
        xq = *(const float2*)(x + (xrow + 2) * INP + kk * 2);
    }
    __syncthreads();

    // prologue pre-step for ts=0: x-tile (kt4) from buf0, C-init = bias
    f32x4 aci, acf, acg, aco;
    {
        const half8 bx = *(const half8*)(&v_s[0][0] + ncol * VSTR + HID + quad * 8);
        aci = __builtin_amdgcn_mfma_f32_16x16x32_f16(A_w[0][4], bx, biasv[0], 0, 0, 0);
        acf = __builtin_amdgcn_mfma_f32_16x16x32_f16(A_w[1][4], bx, biasv[1], 0, 0, 0);
        acg = __builtin_amdgcn_mfma_f32_16x16x32_f16(A_w[2][4], bx, biasv[2], 0, 0, 0);
        aco = __builtin_amdgcn_mfma_f32_16x16x32_f16(A_w[3][4], bx, biasv[3], 0, 0, 0);
    }
    __syncthreads();   // protect buf0 x-region before iter0 overwrites it

    // ---- recurrence: ONE barrier per ts ----
    #pragma unroll 2
    for (int ts = 0; ts < TSTEPS; ++ts) {
        const int pb = ts & 1, nb = pb ^ 1;

        // top: stage x(ts+2) into pb (its old x was consumed pre-barrier
        // last iter); issue load of x(ts+3)
        float2 xn = {0.f, 0.f};
        if (t < 48) {
            const int tsn = (ts + 3 < TSTEPS) ? ts + 3 : TSTEPS - 1;
            xn = *(const float2*)(x + (xrow + tsn) * INP + kk * 2);
            *(unsigned*)&v_s[pb][xb * VSTR + HID + kk * 2] = pack2h(xq.x, xq.y);
        }

        // MFMA phase: h-tiles kt0..3; acc starts at carried (bias + x-tile)
        const _Float16* vh = v_s[pb];
        f32x4 ai = aci, af = acf, ag = acg, ao = aco;
        #pragma unroll
        for (int kt = 0; kt < 4; ++kt) {
            const half8 bh = *(const half8*)(vh + ncol * VSTR + kt * 32 + quad * 8);
            ai = __builtin_amdgcn_mfma_f32_16x16x32_f16(A_w[0][kt], bh, ai, 0, 0, 0);
            af = __builtin_amdgcn_mfma_f32_16x16x32_f16(A_w[1][kt], bh, af, 0, 0, 0);
            ag = __builtin_amdgcn_mfma_f32_16x16x32_f16(A_w[2][kt], bh, ag, 0, 0, 0);
            ao = __builtin_amdgcn_mfma_f32_16x16x32_f16(A_w[3][kt], bh, ao, 0, 0, 0);
        }

        // producer: publish bias-included pre-acts into this wave's slice
        if (ncol < BB) {
            float* gp = pw + ncol * 16 + quad * 4;
            *(f32x4*)(gp + 0 * 64) = ai;
            *(f32x4*)(gp + 1 * 64) = af;
            *(f32x4*)(gp + 2 * 64) = ag;
            *(f32x4*)(gp + 3 * 64) = ao;
        }

        // consumer: all 64 lanes, one cell each (same-wave DS + lgkmcnt)
        {
            const float gi = sigm_f(pw[0 * 64 + ci]);
            const float gf = sigm_f(pw[1 * 64 + ci]);
            const float gg = tanh_f(pw[2 * 64 + ci]);
            const float go = sigm_f(pw[3 * 64 + ci]);
            c_reg = gf * c_reg + gi * gg;
            const float h = go * tanh_f(c_reg);
            v_s[nb][cb * VSTR + uj] = (_Float16)h;
        }

        // pre-barrier x-tile mfma for ts+1 (independent of consumer chain;
        // overlaps it on the mfma pipe). x(ts+1) is in nb since last epoch.
        {
            const half8 bx = *(const half8*)(&v_s[nb][0] + ncol * VSTR + HID + quad * 8);
            aci = __builtin_amdgcn_mfma_f32_16x16x32_f16(A_w[0][4], bx, biasv[0], 0, 0, 0);
            acf = __builtin_amdgcn_mfma_f32_16x16x32_f16(A_w[1][4], bx, biasv[1], 0, 0, 0);
            acg = __builtin_amdgcn_mfma_f32_16x16x32_f16(A_w[2][4], bx, biasv[2], 0, 0, 0);
            aco = __builtin_amdgcn_mfma_f32_16x16x32_f16(A_w[3][4], bx, biasv[3], 0, 0, 0);
        }

        // roll x queue
        if (t < 48) xq = xn;

        // single cross-wave hazard: h(ts) + x(ts+2) visible next epoch
        __syncthreads();
    }

    // ---- FC head: final h is in buffer 0 (ts=511 -> nb=0), offset 0..127 ----
    if (t < 64 * BB) {
        const int b = t >> 6, u = t & 63;
        const float* w = W1 + u * 130;
        float a = b1[u];
        #pragma unroll 16
        for (int k = 0; k < HID; ++k) {
            const float hv = (float)v_s[0][b * VSTR + k];
            a += fmaxf(hv, 0.0f) * w[k];
        }
        const float a0 = addin[(size_t)(b0 + b) * 2 + 0];
        const float a1 = addin[(size_t)(b0 + b) * 2 + 1];
        a += fmaxf(a0, 0.0f) * w[128] + fmaxf(a1, 0.0f) * w[129];
        z_s[b][u] = fmaxf(a, 0.0f);
    }
    __syncthreads();
    if (t < 3 * BB) {
        const int b = t / 3, o = t - 3 * b;
        const float* w = W2 + o * 64;
        float a = b2[o];
        #pragma unroll
        for (int k = 0; k < 64; ++k)
            a += z_s[b][k] * w[k];
        out[(size_t)(b0 + b) * 3 + o] = a;
    }
}

extern "C" void kernel_launch(void* const* d_in, const int* in_sizes, int n_in,
                              void* d_out, int out_size, void* d_ws, size_t ws_size,
                              hipStream_t stream) {
    const float* x     = (const float*)d_in[0];
    const float* addin = (const float*)d_in[1];
    const float* W_ih  = (const float*)d_in[2];
    const float* W_hh  = (const float*)d_in[3];
    const float* b_ih  = (const float*)d_in[4];
    const float* b_hh  = (const float*)d_in[5];
    const float* W1    = (const float*)d_in[6];
    const float* b1    = (const float*)d_in[7];
    const float* W2    = (const float*)d_in[8];
    const float* b2    = (const float*)d_in[9];
    float* outp        = (float*)d_out;

    const int B = in_sizes[0] / (TSTEPS * INP);   // 1024
    const int grid = B / BB;                      // 256 blocks (1 per CU)

    lstm_fused<<<grid, 512, 0, stream>>>(x, addin, W_ih, W_hh, b_ih, b_hh,
                                         W1, b1, W2, b2, outp);
}